// Round 6
// baseline (2005.570 us; speedup 1.0000x reference)
//
#include <hip/hip_runtime.h>
#include <math.h>

#define BATCH 8
#define NPT   2048
#define DIM   32
#define RPB   64                      // rows per block: 4 strips of 16
#define STRIPS (RPB / 16)
#define NBLKR (NPT / RPB)             // 32 row blocks
#define NSLICE 3
#define GRIDN (BATCH * NSLICE * NBLKR)  // 768 blocks = 3/CU, co-resident
#define CPW   (NPT / 4)               // 512 cols per wave
#define NT    (CPW / 16)              // 32 col-tiles of 16 per wave
#define L2E   1.44269504088896f
#define LN2   0.6931471805599453f
#define BN    (BATCH * NPT)

typedef __attribute__((ext_vector_type(8))) _Float16 half8;
typedef __attribute__((ext_vector_type(4))) float floatx4;
typedef unsigned short u16;
typedef unsigned int u32;

__device__ __forceinline__ u16 f2h_bits(float v) {
    _Float16 h = (_Float16)v;
    return *(u16*)&h;
}
__device__ __forceinline__ float exp2v(float x) { return __builtin_amdgcn_exp2f(x); }

struct PArgs {
    const float *x, *a, *y, *b;
    float *c_x, *c_y, *qx, *qy;
    u16 *xh, *yh, *xsh, *ysh;
    float *fb[2], *gb[2], *fxb[2], *fyb[2];
    float *tlsF[2], *tlsG[2], *tlsFx[2], *tlsFy[2];
    float *bmF[2], *bmG[2], *bmFx[2], *bmFy[2];
    float *ctA, *ctX, *ctY, *dummyT, *dummyB;
    float *gpart;          // [BATCH][NBLKR][NPT]
    float *out;
    int *ctr;              // 32 barrier counters, zeroed per replay
};

// Manual grid barrier == what cg::grid_group::sync() lowers to (device-scope
// atomic arrive + agent fences). Used because hipLaunchCooperativeKernel is
// rejected under graph capture (R4 post-mortem). One counter per phase, no
// sense reversal. Bounded spin: residency failure => wrong answer, not hang.
__device__ __forceinline__ void gbar(int* c) {
    __syncthreads();                  // drains this block's stores (vmcnt 0)
    if (threadIdx.x == 0) {
        __threadfence();              // release: L2 writeback (agent scope)
        atomicAdd(c, 1);
        int tries = 0;
        while (__hip_atomic_load(c, __ATOMIC_RELAXED, __HIP_MEMORY_SCOPE_AGENT)
                   < GRIDN && ++tries < 20000000) {
            __builtin_amdgcn_s_sleep(4);
        }
        __threadfence();              // acquire: L1/L2 invalidate
    }
    __syncthreads();
}

// Persistent kernel: init -> 10x{ct(3 slices); bar; gfin; bar} ->
// final ct; bar -> fused gfin+reduce. Phase bodies are verbatim R2 (325us,
// absmax 0.0); only the host launch loop moved in-kernel.
__global__ __launch_bounds__(256, 3) void persist_kernel(PArgs pa) {
    const int bid = blockIdx.x;
    const int tid = threadIdx.x;
    const int w = tid >> 6, lane = tid & 63, n = lane & 15, quad = lane >> 4;
    const int qk = quad * 8;

    __shared__ float lsum[RPB][4];
    __shared__ float sb[128];
    __shared__ float ps[4][64];

    int ph = 0;

    // ---------------- init phase (blocks 0..63) ----------------
    if (bid < BN / 256) {
        const int idx = bid * 256 + tid;
        if (idx == 0) pa.out[0] = 0.f;
        const float* xp = pa.x + (size_t)idx * DIM;
        const float* yp = pa.y + (size_t)idx * DIM;
        u32* xhp  = (u32*)pa.xh  + (size_t)idx * (DIM / 2);
        u32* yhp  = (u32*)pa.yh  + (size_t)idx * (DIM / 2);
        u32* xshp = (u32*)pa.xsh + (size_t)idx * (DIM / 2);
        u32* yshp = (u32*)pa.ysh + (size_t)idx * (DIM / 2);
        float sx = 0.f, sy = 0.f;
        #pragma unroll
        for (int d = 0; d < DIM; d += 2) {
            float v0 = xp[d], v1 = xp[d + 1];
            sx += v0 * v0 + v1 * v1;
            xhp[d / 2]  = (u32)f2h_bits(v0) | ((u32)f2h_bits(v1) << 16);
            xshp[d / 2] = (u32)f2h_bits(L2E * v0) | ((u32)f2h_bits(L2E * v1) << 16);
            float u0 = yp[d], u1 = yp[d + 1];
            sy += u0 * u0 + u1 * u1;
            yhp[d / 2]  = (u32)f2h_bits(u0) | ((u32)f2h_bits(u1) << 16);
            yshp[d / 2] = (u32)f2h_bits(L2E * u0) | ((u32)f2h_bits(L2E * u1) << 16);
        }
        float qxv = 0.5f * sx, qyv = 0.5f * sy;
        pa.qx[idx] = qxv; pa.qy[idx] = qyv;
        float cxv = __logf(pa.a[idx]) - qxv;
        float cyv = __logf(pa.b[idx]) - qyv;
        pa.c_x[idx] = cxv; pa.c_y[idx] = cyv;
        pa.fb[0][idx] = 0.f; pa.gb[0][idx] = 0.f;
        pa.fxb[0][idx] = 0.f; pa.fyb[0][idx] = 0.f;
        pa.tlsF[0][idx] = L2E * cxv; pa.tlsG[0][idx] = L2E * cyv;
        pa.tlsFx[0][idx] = L2E * cxv; pa.tlsFy[0][idx] = L2E * cyv;
        float mx = cxv, my = cyv;
        #pragma unroll
        for (int m = 1; m < 16; m <<= 1) {
            mx = fmaxf(mx, __shfl_xor(mx, m, 64));
            my = fmaxf(my, __shfl_xor(my, m, 64));
        }
        if ((tid & 15) == 0) {
            int g = idx >> 4;
            pa.bmF[0][g] = mx; pa.bmFx[0][g] = mx;
            pa.bmG[0][g] = my; pa.bmFy[0][g] = my;
        }
    }
    gbar(pa.ctr + ph); ph++;

    // ---------------- role decode ----------------
    const int batch = bid / (NSLICE * NBLKR);
    const int rem = bid - batch * (NSLICE * NBLKR);
    const int slice = rem >> 5;           // 0=fused cross, 1=sym x, 2=sym y
    const int xb = rem & 31;
    const int row0 = xb * RPB;
    const size_t pbase = (size_t)batch * NPT * DIM;
    const size_t vbase = (size_t)batch * NPT;
    const int c0 = w * CPW + n;

    const u16* __restrict__ Ahp = (slice == 2 ? pa.yh : pa.xh) + pbase;
    const u16* __restrict__ Bhp = (slice == 1 ? pa.xsh : pa.ysh) + pbase;
    const u16* __restrict__ bbase = Bhp + (size_t)c0 * DIM + qk;
    const float* qXp = (slice == 2 ? pa.qy : pa.qx) + vbase;
    const float* cwp = (slice == 2 ? pa.c_y : pa.c_x) + vbase;
    float* gpc = pa.gpart + ((size_t)batch * NBLKR + xb) * NPT + c0;

    #pragma unroll 1
    for (int it = 0; it <= 10; ++it) {
        const int cur = it & 1;
        const int avg = (it < 10);

        // ================= ct phase (verbatim R2) =================
        half8 ah[STRIPS];
        #pragma unroll
        for (int s = 0; s < STRIPS; s++) {
            size_t off = (size_t)(row0 + s * 16 + n) * DIM + qk;
            ah[s] = *(const half8*)(Ahp + off);
        }

        if (slice == 0) {
            const float* __restrict__ tg = pa.tlsG[cur] + vbase;
            const float* __restrict__ tf = pa.tlsF[cur] + vbase;
            const float* bmGp = pa.bmG[cur];
            const float* bmFp = pa.bmF[cur];
            float* outF   = avg ? pa.fb[cur ^ 1]   : pa.ctA;
            float* tlsOut = avg ? pa.tlsF[cur ^ 1] : pa.dummyT;
            float* bmOut  = avg ? pa.bmF[cur ^ 1]  : pa.dummyB;

            float mg = fmaxf(bmGp[batch * 128 + lane], bmGp[batch * 128 + 64 + lane]);
            float mf = fmaxf(bmFp[batch * 128 + lane], bmFp[batch * 128 + 64 + lane]);
            #pragma unroll
            for (int m = 1; m < 64; m <<= 1) {
                mg = fmaxf(mg, __shfl_xor(mg, m, 64));
                mf = fmaxf(mf, __shfl_xor(mf, m, 64));
            }
            const float TmaxG = mg;
            const float l2eTG = L2E * mg, l2eTF = L2E * mf;

            floatx4 cis[STRIPS];
            #pragma unroll
            for (int s = 0; s < STRIPS; s++)
                #pragma unroll
                for (int r = 0; r < 4; r++)
                    cis[s][r] = tf[row0 + s * 16 + quad * 4 + r] - l2eTF;

            float sumF[STRIPS][4];
            #pragma unroll
            for (int s = 0; s < STRIPS; s++)
                #pragma unroll
                for (int r = 0; r < 4; r++) sumF[s][r] = 0.0f;

            const float* tp = tg + c0;
            half8 b0, b1;
            float t0, t1;
            b0 = *(const half8*)bbase;  t0 = *tp;

            auto tile = [&](half8 b, float t, int idx) {
                float wq = exp2v(t - l2eTG);
                floatx4 acc[STRIPS];
                #pragma unroll
                for (int s = 0; s < STRIPS; s++)
                    acc[s] = __builtin_amdgcn_mfma_f32_16x16x32_f16(ah[s], b, cis[s], 0, 0, 0);
                float e[STRIPS][4];
                #pragma unroll
                for (int s = 0; s < STRIPS; s++)
                    #pragma unroll
                    for (int r = 0; r < 4; r++) {
                        e[s][r] = exp2v(acc[s][r]);
                        sumF[s][r] = fmaf(wq, e[s][r], sumF[s][r]);
                    }
                float gl = (((e[0][0] + e[0][1]) + (e[0][2] + e[0][3]))
                          + ((e[1][0] + e[1][1]) + (e[1][2] + e[1][3])))
                         + (((e[2][0] + e[2][1]) + (e[2][2] + e[2][3]))
                          + ((e[3][0] + e[3][1]) + (e[3][2] + e[3][3])));
                gl += __shfl_xor(gl, 16, 64);
                gl += __shfl_xor(gl, 32, 64);
                if (lane < 16) gpc[idx * 16] = gl;
            };

            #pragma unroll 1
            for (int ch = 0; ch < NT; ch += 2) {
                b1 = *(const half8*)(bbase + (size_t)(ch + 1) * 16 * DIM);
                t1 = tp[(ch + 1) * 16];
                tile(b0, t0, ch);
                if (ch + 2 < NT) {
                    b0 = *(const half8*)(bbase + (size_t)(ch + 2) * 16 * DIM);
                    t0 = tp[(ch + 2) * 16];
                }
                tile(b1, t1, ch + 1);
            }

            #pragma unroll
            for (int s = 0; s < STRIPS; s++)
                #pragma unroll
                for (int r = 0; r < 4; r++) {
                    float v = sumF[s][r];
                    #pragma unroll
                    for (int m = 1; m < 16; m <<= 1) v += __shfl_xor(v, m, 64);
                    if (n == 0) lsum[s * 16 + quad * 4 + r][w] = v;
                }
            __syncthreads();

            if (tid < RPB) {
                float T = (lsum[tid][0] + lsum[tid][1]) + (lsum[tid][2] + lsum[tid][3]);
                int l = row0 + tid;
                float lse = TmaxG + __logf(T) - LN2 * (tf[l] - l2eTF);
                float val = qXp[l] - lse;
                if (avg) val = 0.5f * (pa.fb[cur][vbase + l] + val);
                outF[vbase + l] = val;
                float tc = val + cwp[l];
                tlsOut[vbase + l] = L2E * tc;
                float bm = tc;
                #pragma unroll
                for (int m = 1; m < 16; m <<= 1) bm = fmaxf(bm, __shfl_xor(bm, m, 64));
                if ((tid & 15) == 0)
                    bmOut[batch * 128 + xb * STRIPS + (tid >> 4)] = bm;
            }
        } else {
            const int sy = (slice == 2);
            const float* __restrict__ tls = (sy ? pa.tlsFy[cur] : pa.tlsFx[cur]) + vbase;
            const float* bmIn = sy ? pa.bmFy[cur] : pa.bmFx[cur];
            const float* prev = sy ? pa.fyb[cur] : pa.fxb[cur];
            float* outp   = avg ? (sy ? pa.fyb[cur ^ 1]   : pa.fxb[cur ^ 1])
                                : (sy ? pa.ctY : pa.ctX);
            float* tlsOut = avg ? (sy ? pa.tlsFy[cur ^ 1] : pa.tlsFx[cur ^ 1]) : pa.dummyT;
            float* bmOut  = avg ? (sy ? pa.bmFy[cur ^ 1]  : pa.bmFx[cur ^ 1])  : pa.dummyB;

            float tmv = fmaxf(bmIn[batch * 128 + lane], bmIn[batch * 128 + 64 + lane]);
            #pragma unroll
            for (int m = 1; m < 64; m <<= 1) tmv = fmaxf(tmv, __shfl_xor(tmv, m, 64));
            const float l2eTmax = L2E * tmv;
            const float Tmax = tmv;

            float sum[STRIPS][4];
            #pragma unroll
            for (int s = 0; s < STRIPS; s++)
                #pragma unroll
                for (int r = 0; r < 4; r++) sum[s][r] = 0.0f;

            const float* tp = tls + c0;
            half8 b0, b1;
            float t0, t1;
            b0 = *(const half8*)bbase;  t0 = *tp;

            auto tile = [&](half8 b, float t) {
                float bias = t - l2eTmax;
                floatx4 ci = (floatx4){bias, bias, bias, bias};
                floatx4 acc[STRIPS];
                #pragma unroll
                for (int s = 0; s < STRIPS; s++)
                    acc[s] = __builtin_amdgcn_mfma_f32_16x16x32_f16(ah[s], b, ci, 0, 0, 0);
                #pragma unroll
                for (int s = 0; s < STRIPS; s++)
                    #pragma unroll
                    for (int r = 0; r < 4; r++)
                        sum[s][r] += exp2v(acc[s][r]);
            };

            #pragma unroll 1
            for (int ch = 0; ch < NT; ch += 2) {
                b1 = *(const half8*)(bbase + (size_t)(ch + 1) * 16 * DIM);
                t1 = tp[(ch + 1) * 16];
                tile(b0, t0);
                if (ch + 2 < NT) {
                    b0 = *(const half8*)(bbase + (size_t)(ch + 2) * 16 * DIM);
                    t0 = tp[(ch + 2) * 16];
                }
                tile(b1, t1);
            }

            #pragma unroll
            for (int s = 0; s < STRIPS; s++)
                #pragma unroll
                for (int r = 0; r < 4; r++) {
                    float v = sum[s][r];
                    #pragma unroll
                    for (int m = 1; m < 16; m <<= 1) v += __shfl_xor(v, m, 64);
                    if (n == 0) lsum[s * 16 + quad * 4 + r][w] = v;
                }
            __syncthreads();

            if (tid < RPB) {
                float T = (lsum[tid][0] + lsum[tid][1]) + (lsum[tid][2] + lsum[tid][3]);
                int l = row0 + tid;
                float lse = Tmax + __logf(T);
                float val = qXp[l] - lse;
                if (avg) val = 0.5f * (prev[vbase + l] + val);
                outp[vbase + l] = val;
                float tc = val + cwp[l];
                tlsOut[vbase + l] = L2E * tc;
                float bm = tc;
                #pragma unroll
                for (int m = 1; m < 16; m <<= 1) bm = fmaxf(bm, __shfl_xor(bm, m, 64));
                if ((tid & 15) == 0)
                    bmOut[batch * 128 + xb * STRIPS + (tid >> 4)] = bm;
            }
        }
        gbar(pa.ctr + ph); ph++;

        if (it == 10) break;          // final gfin fused into reduce below

        // ================= gfin phase (verbatim R2, blocks 0..255) ======
        if (bid < 256) {
            const int fbatch = bid >> 5;
            const int chunk = bid & 31;
            const int g = tid >> 6, c = tid & 63;
            const int col = chunk * 64 + c;
            const float* bmFp = pa.bmF[cur];
            float* outG   = pa.gb[cur ^ 1];
            float* tlsOut = pa.tlsG[cur ^ 1];
            float* bmOut  = pa.bmG[cur ^ 1];

            if (tid < 128) sb[tid] = bmFp[fbatch * 128 + tid];
            __syncthreads();
            float m = fmaxf(sb[tid & 63], sb[(tid & 63) + 64]);
            #pragma unroll
            for (int k = 1; k < 64; k <<= 1) m = fmaxf(m, __shfl_xor(m, k, 64));
            const float Tmax = m;

            const float* gp = pa.gpart + ((size_t)fbatch * NBLKR + g) * NPT + col;
            float G = 0.0f;
            #pragma unroll
            for (int p = 0; p < NBLKR / 4; p++) G += gp[(size_t)p * 4 * NPT];
            ps[g][c] = G;
            __syncthreads();

            if (tid < 64) {
                float Gt = (ps[0][tid] + ps[1][tid]) + (ps[2][tid] + ps[3][tid]);
                const int colT = chunk * 64 + tid;
                const size_t idx = (size_t)fbatch * NPT + colT;
                float val = pa.qy[idx] - (Tmax + __logf(Gt));
                val = 0.5f * (pa.gb[cur][idx] + val);
                outG[idx] = val;
                float tc = val + pa.c_y[idx];
                tlsOut[idx] = L2E * tc;
                float bm = tc;
                #pragma unroll
                for (int k = 1; k < 16; k <<= 1) bm = fmaxf(bm, __shfl_xor(bm, k, 64));
                if ((tid & 15) == 0) bmOut[fbatch * 128 + (colT >> 4)] = bm;
            }
            __syncthreads();
        }
        gbar(pa.ctr + ph); ph++;
    }

    // ======== final: fused gfin + divergence reduce (blocks 0..255) ======
    // it=10 ran with cur=0: gpart + bmF[0] are final; ctA/ctX/ctY written.
    if (bid < 256) {
        const int fbatch = bid >> 5;
        const int chunk = bid & 31;
        const int g = tid >> 6, c = tid & 63;
        const int col = chunk * 64 + c;
        const float* bmFp = pa.bmF[0];

        if (tid < 128) sb[tid] = bmFp[fbatch * 128 + tid];
        __syncthreads();
        float m = fmaxf(sb[tid & 63], sb[(tid & 63) + 64]);
        #pragma unroll
        for (int k = 1; k < 64; k <<= 1) m = fmaxf(m, __shfl_xor(m, k, 64));
        const float Tmax = m;

        const float* gp = pa.gpart + ((size_t)fbatch * NBLKR + g) * NPT + col;
        float G = 0.0f;
        #pragma unroll
        for (int p = 0; p < NBLKR / 4; p++) G += gp[(size_t)p * 4 * NPT];
        ps[g][c] = G;
        __syncthreads();

        if (tid < 64) {
            float Gt = (ps[0][tid] + ps[1][tid]) + (ps[2][tid] + ps[3][tid]);
            const int colT = chunk * 64 + tid;
            const size_t idx = (size_t)fbatch * NPT + colT;
            float ctB = pa.qy[idx] - (Tmax + __logf(Gt));
            float acc = pa.a[idx] * (pa.ctA[idx] - pa.ctX[idx])
                      + pa.b[idx] * (ctB - pa.ctY[idx]);
            #pragma unroll
            for (int off = 32; off > 0; off >>= 1) acc += __shfl_down(acc, off, 64);
            if (tid == 0) atomicAdd(pa.out, acc * (1.0f / (float)BATCH));
        }
    }
}

__global__ void zeroctr_kernel(int* ctr) {
    if (threadIdx.x < 32) ctr[threadIdx.x] = 0;
}

extern "C" void kernel_launch(void* const* d_in, const int* in_sizes, int n_in,
                              void* d_out, int out_size, void* d_ws, size_t ws_size,
                              hipStream_t stream) {
    const float* x = (const float*)d_in[0];
    const float* a = (const float*)d_in[1];
    const float* y = (const float*)d_in[2];
    const float* b = (const float*)d_in[3];
    float* out = (float*)d_out;

    float* ws = (float*)d_ws;
    float* c_x = ws + 0 * BN;
    float* c_y = ws + 1 * BN;
    float* qx  = ws + 2 * BN;
    float* qy  = ws + 3 * BN;
    float* fb[2]  = { ws + 4 * BN,  ws + 5 * BN };
    float* gbb[2] = { ws + 6 * BN,  ws + 7 * BN };
    float* fxb[2] = { ws + 8 * BN,  ws + 9 * BN };
    float* fyb[2] = { ws + 10 * BN, ws + 11 * BN };
    float* ctA = ws + 12 * BN;
    float* ctX = ws + 14 * BN;
    float* ctY = ws + 15 * BN;
    float* tlsF[2]  = { ws + 16 * BN, ws + 17 * BN };
    float* tlsG[2]  = { ws + 18 * BN, ws + 19 * BN };
    float* tlsFx[2] = { ws + 20 * BN, ws + 21 * BN };
    float* tlsFy[2] = { ws + 22 * BN, ws + 23 * BN };
    float* dummyT = ws + 24 * BN;
    float* small = ws + 25 * BN;
    float* bmF[2]  = { small + 0 * 1024, small + 1 * 1024 };
    float* bmG[2]  = { small + 2 * 1024, small + 3 * 1024 };
    float* bmFx[2] = { small + 4 * 1024, small + 5 * 1024 };
    float* bmFy[2] = { small + 6 * 1024, small + 7 * 1024 };
    float* dummyB = small + 8 * 1024;
    int* ctr = (int*)(small + 9 * 1024);
    u16* bf = (u16*)(small + 10 * 1024);
    const size_t AS = (size_t)BN * DIM;
    u16* xh  = bf + 0 * AS;
    u16* yh  = bf + 1 * AS;
    u16* xsh = bf + 2 * AS;
    u16* ysh = bf + 3 * AS;
    float* gpart = (float*)(bf + 4 * AS);   // [BATCH][NBLKR][NPT] = 2 MB

    PArgs pa;
    pa.x = x; pa.a = a; pa.y = y; pa.b = b;
    pa.c_x = c_x; pa.c_y = c_y; pa.qx = qx; pa.qy = qy;
    pa.xh = xh; pa.yh = yh; pa.xsh = xsh; pa.ysh = ysh;
    pa.fb[0] = fb[0]; pa.fb[1] = fb[1];
    pa.gb[0] = gbb[0]; pa.gb[1] = gbb[1];
    pa.fxb[0] = fxb[0]; pa.fxb[1] = fxb[1];
    pa.fyb[0] = fyb[0]; pa.fyb[1] = fyb[1];
    pa.tlsF[0] = tlsF[0]; pa.tlsF[1] = tlsF[1];
    pa.tlsG[0] = tlsG[0]; pa.tlsG[1] = tlsG[1];
    pa.tlsFx[0] = tlsFx[0]; pa.tlsFx[1] = tlsFx[1];
    pa.tlsFy[0] = tlsFy[0]; pa.tlsFy[1] = tlsFy[1];
    pa.bmF[0] = bmF[0]; pa.bmF[1] = bmF[1];
    pa.bmG[0] = bmG[0]; pa.bmG[1] = bmG[1];
    pa.bmFx[0] = bmFx[0]; pa.bmFx[1] = bmFx[1];
    pa.bmFy[0] = bmFy[0]; pa.bmFy[1] = bmFy[1];
    pa.ctA = ctA; pa.ctX = ctX; pa.ctY = ctY;
    pa.dummyT = dummyT; pa.dummyB = dummyB;
    pa.gpart = gpart;
    pa.out = out;
    pa.ctr = ctr;

    zeroctr_kernel<<<1, 64, 0, stream>>>(ctr);
    persist_kernel<<<GRIDN, 256, 0, stream>>>(pa);
}

// Round 7
// 832.268 us; speedup vs baseline: 2.4098x; 2.4098x over previous
//
#include <hip/hip_runtime.h>
#include <math.h>

#define BATCH 8
#define NPT   2048
#define DIM   32
#define RPB   64                      // rows per block: 4 strips of 16
#define STRIPS (RPB / 16)
#define NBLKR (NPT / RPB)             // 32 row blocks
#define NSLICE 3
#define GRIDN (BATCH * NSLICE * NBLKR)  // 768 blocks = 3/CU, co-resident
#define CPW   (NPT / 4)               // 512 cols per wave
#define NT    (CPW / 16)              // 32 col-tiles of 16 per wave
#define L2E   1.44269504088896f
#define LN2   0.6931471805599453f
#define BN    (BATCH * NPT)
#define SPIN_LIMIT 4000000

typedef __attribute__((ext_vector_type(8))) _Float16 half8;
typedef __attribute__((ext_vector_type(4))) float floatx4;
typedef unsigned short u16;
typedef unsigned int u32;

__device__ __forceinline__ u16 f2h_bits(float v) {
    _Float16 h = (_Float16)v;
    return *(u16*)&h;
}
__device__ __forceinline__ float exp2v(float x) { return __builtin_amdgcn_exp2f(x); }

struct PArgs {
    const float *x, *a, *y, *b;
    float *c_x, *c_y, *qx, *qy;
    u16 *xh, *yh, *xsh, *ysh;
    float *fb[2], *gb[2], *fxb[2], *fyb[2];
    float *tlsF[2], *tlsG[2], *tlsFx[2], *tlsFy[2];
    float *bmF[2], *bmG[2], *bmFx[2], *bmFy[2];
    float *ctA, *ctB, *ctX, *ctY, *dummyT, *dummyB;
    float *gpart;          // [BATCH][NBLKR][NPT]
    float *out;
    int *flags;            // initD[64] ctD[8][32] gfD[8][32] sxD[8][32] syD[8][32]
};

// Release-post: one plain agent-scope STORE per block (no RMW -> no
// serialization; R6 measured 768 atomicAdds on one line = ~85us/barrier).
// Fence-then-store pattern is R6-proven correct cross-XCD (absmax 0.0).
__device__ __forceinline__ void postSlot(int* slot, int val) {
    __syncthreads();                  // all block stores drained (vmcnt 0)
    if (threadIdx.x == 0) {
        __threadfence();              // release to agent scope
        __hip_atomic_store(slot, val, __ATOMIC_RELAXED, __HIP_MEMORY_SCOPE_AGENT);
    }
}

// Wave-0 lanes poll cnt slots (one coalesced load per poll). Bounded spin:
// residency failure => wrong answer, not hang.
__device__ __forceinline__ void waitSlots(const int* slots, int cnt, int target) {
    if (threadIdx.x < 64) {
        const int* p = slots + (threadIdx.x & (cnt - 1));
        int tries = 0;
        while (__hip_atomic_load(p, __ATOMIC_RELAXED, __HIP_MEMORY_SCOPE_AGENT) < target
               && ++tries < SPIN_LIMIT) {
            __builtin_amdgcn_s_sleep(2);
        }
    }
    __syncthreads();
    if (threadIdx.x == 0) __threadfence();   // acquire (R6-proven pattern)
    __syncthreads();
}

// Persistent kernel, batch-local flag sync (no global barriers):
//   init (64 blocks) -> post initD
//   slice0 (256 blocks, 32/batch): 11x { wait gfD>=it; ct-fused; post ctD;
//          wait ctD>=it+1; gfin 64-col chunk; post gfD } -> reduce
//   slice1/2 (512 blocks): 11x { wait s*D>=it; ct-sym; post s*D }
// Phase bodies verbatim R2/R6 (both passed absmax 0.0).
__global__ __launch_bounds__(256, 3) void persist_kernel(PArgs pa) {
    const int bid = blockIdx.x;
    const int tid = threadIdx.x;
    const int w = tid >> 6, lane = tid & 63, n = lane & 15, quad = lane >> 4;
    const int qk = quad * 8;

    __shared__ float lsum[RPB][4];
    __shared__ float ps[4][64];

    int* initD = pa.flags;
    int* ctD   = pa.flags + 64;
    int* gfD   = ctD + 256;
    int* sxD   = gfD + 256;
    int* syD   = sxD + 256;

    // ---------------- init phase (blocks 0..63) ----------------
    if (bid < BN / 256) {
        const int idx = bid * 256 + tid;
        const float* xp = pa.x + (size_t)idx * DIM;
        const float* yp = pa.y + (size_t)idx * DIM;
        u32* xhp  = (u32*)pa.xh  + (size_t)idx * (DIM / 2);
        u32* yhp  = (u32*)pa.yh  + (size_t)idx * (DIM / 2);
        u32* xshp = (u32*)pa.xsh + (size_t)idx * (DIM / 2);
        u32* yshp = (u32*)pa.ysh + (size_t)idx * (DIM / 2);
        float sx = 0.f, sy = 0.f;
        #pragma unroll
        for (int d = 0; d < DIM; d += 2) {
            float v0 = xp[d], v1 = xp[d + 1];
            sx += v0 * v0 + v1 * v1;
            xhp[d / 2]  = (u32)f2h_bits(v0) | ((u32)f2h_bits(v1) << 16);
            xshp[d / 2] = (u32)f2h_bits(L2E * v0) | ((u32)f2h_bits(L2E * v1) << 16);
            float u0 = yp[d], u1 = yp[d + 1];
            sy += u0 * u0 + u1 * u1;
            yhp[d / 2]  = (u32)f2h_bits(u0) | ((u32)f2h_bits(u1) << 16);
            yshp[d / 2] = (u32)f2h_bits(L2E * u0) | ((u32)f2h_bits(L2E * u1) << 16);
        }
        float qxv = 0.5f * sx, qyv = 0.5f * sy;
        pa.qx[idx] = qxv; pa.qy[idx] = qyv;
        float cxv = __logf(pa.a[idx]) - qxv;
        float cyv = __logf(pa.b[idx]) - qyv;
        pa.c_x[idx] = cxv; pa.c_y[idx] = cyv;
        pa.fb[0][idx] = 0.f; pa.gb[0][idx] = 0.f;
        pa.fxb[0][idx] = 0.f; pa.fyb[0][idx] = 0.f;
        pa.tlsF[0][idx] = L2E * cxv; pa.tlsG[0][idx] = L2E * cyv;
        pa.tlsFx[0][idx] = L2E * cxv; pa.tlsFy[0][idx] = L2E * cyv;
        float mx = cxv, my = cyv;
        #pragma unroll
        for (int m = 1; m < 16; m <<= 1) {
            mx = fmaxf(mx, __shfl_xor(mx, m, 64));
            my = fmaxf(my, __shfl_xor(my, m, 64));
        }
        if ((tid & 15) == 0) {
            int g = idx >> 4;
            pa.bmF[0][g] = mx; pa.bmFx[0][g] = mx;
            pa.bmG[0][g] = my; pa.bmFy[0][g] = my;
        }
        postSlot(initD + bid, 1);
    }
    waitSlots(initD, 64, 1);

    // ---------------- role decode ----------------
    const int batch = bid / (NSLICE * NBLKR);
    const int rem = bid - batch * (NSLICE * NBLKR);
    const int slice = rem >> 5;           // 0=fused cross, 1=sym x, 2=sym y
    const int xb = rem & 31;
    const int row0 = xb * RPB;
    const size_t pbase = (size_t)batch * NPT * DIM;
    const size_t vbase = (size_t)batch * NPT;
    const int c0 = w * CPW + n;

    const u16* __restrict__ Ahp = (slice == 2 ? pa.yh : pa.xh) + pbase;
    const u16* __restrict__ Bhp = (slice == 1 ? pa.xsh : pa.ysh) + pbase;
    const u16* __restrict__ bbase = Bhp + (size_t)c0 * DIM + qk;
    const float* qXp = (slice == 2 ? pa.qy : pa.qx) + vbase;
    const float* cwp = (slice == 2 ? pa.c_y : pa.c_x) + vbase;
    float* gpc = pa.gpart + ((size_t)batch * NBLKR + xb) * NPT + c0;

    half8 ah[STRIPS];
    #pragma unroll
    for (int s = 0; s < STRIPS; s++) {
        size_t off = (size_t)(row0 + s * 16 + n) * DIM + qk;
        ah[s] = *(const half8*)(Ahp + off);
    }

    if (slice == 0) {
        int* ctDb = ctD + batch * 32;
        int* gfDb = gfD + batch * 32;

        #pragma unroll 1
        for (int it = 0; it <= 10; ++it) {
            const int cur = it & 1;
            const int avg = (it < 10);
            if (it > 0) waitSlots(gfDb, 32, it);    // implies ctD>=it transitively

            // ============ fused cross ct (verbatim R6) ============
            {
                const float* __restrict__ tg = pa.tlsG[cur] + vbase;
                const float* __restrict__ tf = pa.tlsF[cur] + vbase;
                const float* bmGp = pa.bmG[cur];
                const float* bmFp = pa.bmF[cur];
                float* outF   = avg ? pa.fb[cur ^ 1]   : pa.ctA;
                float* tlsOut = avg ? pa.tlsF[cur ^ 1] : pa.dummyT;
                float* bmOut  = avg ? pa.bmF[cur ^ 1]  : pa.dummyB;

                float mg = fmaxf(bmGp[batch * 128 + lane], bmGp[batch * 128 + 64 + lane]);
                float mf = fmaxf(bmFp[batch * 128 + lane], bmFp[batch * 128 + 64 + lane]);
                #pragma unroll
                for (int m = 1; m < 64; m <<= 1) {
                    mg = fmaxf(mg, __shfl_xor(mg, m, 64));
                    mf = fmaxf(mf, __shfl_xor(mf, m, 64));
                }
                const float TmaxG = mg;
                const float l2eTG = L2E * mg, l2eTF = L2E * mf;

                floatx4 cis[STRIPS];
                #pragma unroll
                for (int s = 0; s < STRIPS; s++)
                    #pragma unroll
                    for (int r = 0; r < 4; r++)
                        cis[s][r] = tf[row0 + s * 16 + quad * 4 + r] - l2eTF;

                float sumF[STRIPS][4];
                #pragma unroll
                for (int s = 0; s < STRIPS; s++)
                    #pragma unroll
                    for (int r = 0; r < 4; r++) sumF[s][r] = 0.0f;

                const float* tp = tg + c0;
                half8 b0, b1;
                float t0, t1;
                b0 = *(const half8*)bbase;  t0 = *tp;

                auto tile = [&](half8 b, float t, int idx) {
                    float wq = exp2v(t - l2eTG);
                    floatx4 acc[STRIPS];
                    #pragma unroll
                    for (int s = 0; s < STRIPS; s++)
                        acc[s] = __builtin_amdgcn_mfma_f32_16x16x32_f16(ah[s], b, cis[s], 0, 0, 0);
                    float e[STRIPS][4];
                    #pragma unroll
                    for (int s = 0; s < STRIPS; s++)
                        #pragma unroll
                        for (int r = 0; r < 4; r++) {
                            e[s][r] = exp2v(acc[s][r]);
                            sumF[s][r] = fmaf(wq, e[s][r], sumF[s][r]);
                        }
                    float gl = (((e[0][0] + e[0][1]) + (e[0][2] + e[0][3]))
                              + ((e[1][0] + e[1][1]) + (e[1][2] + e[1][3])))
                             + (((e[2][0] + e[2][1]) + (e[2][2] + e[2][3]))
                              + ((e[3][0] + e[3][1]) + (e[3][2] + e[3][3])));
                    gl += __shfl_xor(gl, 16, 64);
                    gl += __shfl_xor(gl, 32, 64);
                    if (lane < 16) gpc[idx * 16] = gl;
                };

                #pragma unroll 1
                for (int ch = 0; ch < NT; ch += 2) {
                    b1 = *(const half8*)(bbase + (size_t)(ch + 1) * 16 * DIM);
                    t1 = tp[(ch + 1) * 16];
                    tile(b0, t0, ch);
                    if (ch + 2 < NT) {
                        b0 = *(const half8*)(bbase + (size_t)(ch + 2) * 16 * DIM);
                        t0 = tp[(ch + 2) * 16];
                    }
                    tile(b1, t1, ch + 1);
                }

                #pragma unroll
                for (int s = 0; s < STRIPS; s++)
                    #pragma unroll
                    for (int r = 0; r < 4; r++) {
                        float v = sumF[s][r];
                        #pragma unroll
                        for (int m = 1; m < 16; m <<= 1) v += __shfl_xor(v, m, 64);
                        if (n == 0) lsum[s * 16 + quad * 4 + r][w] = v;
                    }
                __syncthreads();

                if (tid < RPB) {
                    float T = (lsum[tid][0] + lsum[tid][1]) + (lsum[tid][2] + lsum[tid][3]);
                    int l = row0 + tid;
                    float lse = TmaxG + __logf(T) - LN2 * (tf[l] - l2eTF);
                    float val = qXp[l] - lse;
                    if (avg) val = 0.5f * (pa.fb[cur][vbase + l] + val);
                    outF[vbase + l] = val;
                    float tc = val + cwp[l];
                    tlsOut[vbase + l] = L2E * tc;
                    float bm = tc;
                    #pragma unroll
                    for (int m = 1; m < 16; m <<= 1) bm = fmaxf(bm, __shfl_xor(bm, m, 64));
                    if ((tid & 15) == 0)
                        bmOut[batch * 128 + xb * STRIPS + (tid >> 4)] = bm;
                }
            }
            postSlot(ctDb + xb, it + 1);
            waitSlots(ctDb, 32, it + 1);

            // ============ gfin chunk: cols [xb*64, xb*64+64) ============
            {
                const float* bmFp = pa.bmF[cur];
                float m = fmaxf(bmFp[batch * 128 + lane], bmFp[batch * 128 + 64 + lane]);
                #pragma unroll
                for (int k = 1; k < 64; k <<= 1) m = fmaxf(m, __shfl_xor(m, k, 64));
                const float Tmax = m;

                const int c = tid & 63, pg = tid >> 6;
                const int col = xb * 64 + c;
                const float* gp = pa.gpart + ((size_t)batch * NBLKR + pg * 8) * NPT + col;
                float G = 0.0f;
                #pragma unroll
                for (int p = 0; p < 8; p++) G += gp[(size_t)p * NPT];
                ps[pg][c] = G;
                __syncthreads();

                if (tid < 64) {
                    float Gt = (ps[0][tid] + ps[1][tid]) + (ps[2][tid] + ps[3][tid]);
                    const int colT = xb * 64 + tid;
                    const size_t idx = vbase + colT;
                    float raw = pa.qy[idx] - (Tmax + __logf(Gt));
                    if (avg) {
                        float val = 0.5f * (pa.gb[cur][idx] + raw);
                        pa.gb[cur ^ 1][idx] = val;
                        float tc = val + pa.c_y[idx];
                        pa.tlsG[cur ^ 1][idx] = L2E * tc;
                        float bm = tc;
                        #pragma unroll
                        for (int k = 1; k < 16; k <<= 1) bm = fmaxf(bm, __shfl_xor(bm, k, 64));
                        if ((tid & 15) == 0)
                            pa.bmG[cur ^ 1][batch * 128 + (colT >> 4)] = bm;
                    } else {
                        pa.ctB[idx] = raw;
                    }
                }
            }
            postSlot(gfDb + xb, it + 1);
        }

        // ============ final partial reduce: 64 indices ============
        waitSlots(sxD + batch * 32, 32, 11);
        waitSlots(syD + batch * 32, 32, 11);
        waitSlots(gfDb, 32, 11);
        if (tid < 64) {
            const size_t idx = vbase + xb * 64 + tid;
            float acc = pa.a[idx] * (pa.ctA[idx] - pa.ctX[idx])
                      + pa.b[idx] * (pa.ctB[idx] - pa.ctY[idx]);
            #pragma unroll
            for (int off = 32; off > 0; off >>= 1) acc += __shfl_down(acc, off, 64);
            if (tid == 0) atomicAdd(pa.out, acc * (1.0f / (float)BATCH));
        }
    } else {
        // ================= symmetric slices =================
        const int sy = (slice == 2);
        int* sDb = (sy ? syD : sxD) + batch * 32;

        #pragma unroll 1
        for (int it = 0; it <= 10; ++it) {
            const int cur = it & 1;
            const int avg = (it < 10);
            if (it > 0) waitSlots(sDb, 32, it);

            const float* __restrict__ tls = (sy ? pa.tlsFy[cur] : pa.tlsFx[cur]) + vbase;
            const float* bmIn = sy ? pa.bmFy[cur] : pa.bmFx[cur];
            const float* prev = sy ? pa.fyb[cur] : pa.fxb[cur];
            float* outp   = avg ? (sy ? pa.fyb[cur ^ 1]   : pa.fxb[cur ^ 1])
                                : (sy ? pa.ctY : pa.ctX);
            float* tlsOut = avg ? (sy ? pa.tlsFy[cur ^ 1] : pa.tlsFx[cur ^ 1]) : pa.dummyT;
            float* bmOut  = avg ? (sy ? pa.bmFy[cur ^ 1]  : pa.bmFx[cur ^ 1])  : pa.dummyB;

            float tmv = fmaxf(bmIn[batch * 128 + lane], bmIn[batch * 128 + 64 + lane]);
            #pragma unroll
            for (int m = 1; m < 64; m <<= 1) tmv = fmaxf(tmv, __shfl_xor(tmv, m, 64));
            const float l2eTmax = L2E * tmv;
            const float Tmax = tmv;

            float sum[STRIPS][4];
            #pragma unroll
            for (int s = 0; s < STRIPS; s++)
                #pragma unroll
                for (int r = 0; r < 4; r++) sum[s][r] = 0.0f;

            const float* tp = tls + c0;
            half8 b0, b1;
            float t0, t1;
            b0 = *(const half8*)bbase;  t0 = *tp;

            auto tile = [&](half8 b, float t) {
                float bias = t - l2eTmax;
                floatx4 ci = (floatx4){bias, bias, bias, bias};
                floatx4 acc[STRIPS];
                #pragma unroll
                for (int s = 0; s < STRIPS; s++)
                    acc[s] = __builtin_amdgcn_mfma_f32_16x16x32_f16(ah[s], b, ci, 0, 0, 0);
                #pragma unroll
                for (int s = 0; s < STRIPS; s++)
                    #pragma unroll
                    for (int r = 0; r < 4; r++)
                        sum[s][r] += exp2v(acc[s][r]);
            };

            #pragma unroll 1
            for (int ch = 0; ch < NT; ch += 2) {
                b1 = *(const half8*)(bbase + (size_t)(ch + 1) * 16 * DIM);
                t1 = tp[(ch + 1) * 16];
                tile(b0, t0);
                if (ch + 2 < NT) {
                    b0 = *(const half8*)(bbase + (size_t)(ch + 2) * 16 * DIM);
                    t0 = tp[(ch + 2) * 16];
                }
                tile(b1, t1);
            }

            #pragma unroll
            for (int s = 0; s < STRIPS; s++)
                #pragma unroll
                for (int r = 0; r < 4; r++) {
                    float v = sum[s][r];
                    #pragma unroll
                    for (int m = 1; m < 16; m <<= 1) v += __shfl_xor(v, m, 64);
                    if (n == 0) lsum[s * 16 + quad * 4 + r][w] = v;
                }
            __syncthreads();

            if (tid < RPB) {
                float T = (lsum[tid][0] + lsum[tid][1]) + (lsum[tid][2] + lsum[tid][3]);
                int l = row0 + tid;
                float lse = Tmax + __logf(T);
                float val = qXp[l] - lse;
                if (avg) val = 0.5f * (prev[vbase + l] + val);
                outp[vbase + l] = val;
                float tc = val + cwp[l];
                tlsOut[vbase + l] = L2E * tc;
                float bm = tc;
                #pragma unroll
                for (int m = 1; m < 16; m <<= 1) bm = fmaxf(bm, __shfl_xor(bm, m, 64));
                if ((tid & 15) == 0)
                    bmOut[batch * 128 + xb * STRIPS + (tid >> 4)] = bm;
            }
            postSlot(sDb + xb, it + 1);
        }
    }
}

__global__ void zeroflags_kernel(int* flags, float* out) {
    int i = blockIdx.x * 256 + threadIdx.x;
    if (i < 2048) flags[i] = 0;
    if (i == 0) out[0] = 0.f;
}

extern "C" void kernel_launch(void* const* d_in, const int* in_sizes, int n_in,
                              void* d_out, int out_size, void* d_ws, size_t ws_size,
                              hipStream_t stream) {
    const float* x = (const float*)d_in[0];
    const float* a = (const float*)d_in[1];
    const float* y = (const float*)d_in[2];
    const float* b = (const float*)d_in[3];
    float* out = (float*)d_out;

    float* ws = (float*)d_ws;
    float* c_x = ws + 0 * BN;
    float* c_y = ws + 1 * BN;
    float* qx  = ws + 2 * BN;
    float* qy  = ws + 3 * BN;
    float* fb[2]  = { ws + 4 * BN,  ws + 5 * BN };
    float* gbb[2] = { ws + 6 * BN,  ws + 7 * BN };
    float* fxb[2] = { ws + 8 * BN,  ws + 9 * BN };
    float* fyb[2] = { ws + 10 * BN, ws + 11 * BN };
    float* ctA = ws + 12 * BN;
    float* ctB = ws + 13 * BN;
    float* ctX = ws + 14 * BN;
    float* ctY = ws + 15 * BN;
    float* tlsF[2]  = { ws + 16 * BN, ws + 17 * BN };
    float* tlsG[2]  = { ws + 18 * BN, ws + 19 * BN };
    float* tlsFx[2] = { ws + 20 * BN, ws + 21 * BN };
    float* tlsFy[2] = { ws + 22 * BN, ws + 23 * BN };
    float* dummyT = ws + 24 * BN;
    float* small = ws + 25 * BN;
    float* bmF[2]  = { small + 0 * 1024, small + 1 * 1024 };
    float* bmG[2]  = { small + 2 * 1024, small + 3 * 1024 };
    float* bmFx[2] = { small + 4 * 1024, small + 5 * 1024 };
    float* bmFy[2] = { small + 6 * 1024, small + 7 * 1024 };
    float* dummyB = small + 8 * 1024;
    u16* bf = (u16*)(small + 10 * 1024);
    const size_t AS = (size_t)BN * DIM;
    u16* xh  = bf + 0 * AS;
    u16* yh  = bf + 1 * AS;
    u16* xsh = bf + 2 * AS;
    u16* ysh = bf + 3 * AS;
    float* gpart = (float*)(bf + 4 * AS);   // [BATCH][NBLKR][NPT] = 2 MB
    int* flags = (int*)(gpart + (size_t)BATCH * NBLKR * NPT);  // 2048 ints

    PArgs pa;
    pa.x = x; pa.a = a; pa.y = y; pa.b = b;
    pa.c_x = c_x; pa.c_y = c_y; pa.qx = qx; pa.qy = qy;
    pa.xh = xh; pa.yh = yh; pa.xsh = xsh; pa.ysh = ysh;
    pa.fb[0] = fb[0]; pa.fb[1] = fb[1];
    pa.gb[0] = gbb[0]; pa.gb[1] = gbb[1];
    pa.fxb[0] = fxb[0]; pa.fxb[1] = fxb[1];
    pa.fyb[0] = fyb[0]; pa.fyb[1] = fyb[1];
    pa.tlsF[0] = tlsF[0]; pa.tlsF[1] = tlsF[1];
    pa.tlsG[0] = tlsG[0]; pa.tlsG[1] = tlsG[1];
    pa.tlsFx[0] = tlsFx[0]; pa.tlsFx[1] = tlsFx[1];
    pa.tlsFy[0] = tlsFy[0]; pa.tlsFy[1] = tlsFy[1];
    pa.bmF[0] = bmF[0]; pa.bmF[1] = bmF[1];
    pa.bmG[0] = bmG[0]; pa.bmG[1] = bmG[1];
    pa.bmFx[0] = bmFx[0]; pa.bmFx[1] = bmFx[1];
    pa.bmFy[0] = bmFy[0]; pa.bmFy[1] = bmFy[1];
    pa.ctA = ctA; pa.ctB = ctB; pa.ctX = ctX; pa.ctY = ctY;
    pa.dummyT = dummyT; pa.dummyB = dummyB;
    pa.gpart = gpart;
    pa.out = out;
    pa.flags = flags;

    zeroflags_kernel<<<8, 256, 0, stream>>>(flags, out);
    persist_kernel<<<GRIDN, 256, 0, stream>>>(pa);
}

// Round 8
// 330.651 us; speedup vs baseline: 6.0655x; 2.5171x over previous
//
#include <hip/hip_runtime.h>
#include <math.h>

#define BATCH 8
#define NPT   2048
#define DIM   32
#define RPB   32                      // rows per block: 2 strips of 16
#define STRIPS (RPB / 16)
#define CPW   (NPT / 4)               // 512 cols per wave
#define NT    (CPW / 16)              // 32 col-tiles of 16 per wave
#define L2E   1.44269504088896f
#define BN    (BATCH * NPT)

typedef __attribute__((ext_vector_type(8))) _Float16 half8;
typedef __attribute__((ext_vector_type(4))) float floatx4;
typedef unsigned short u16;
typedef unsigned int u32;

__device__ __forceinline__ u16 f2h_bits(float v) {
    _Float16 h = (_Float16)v;
    return *(u16*)&h;
}
__device__ __forceinline__ float exp2v(float x) { return __builtin_amdgcn_exp2f(x); }

struct CtSet {
    const u16* Ah;        // row-side plain fp16 [BATCH][NPT][DIM]
    const u16* Bh;        // col-side log2e-scaled fp16
    const float* tls;     // log2e*(pot+cw) on cols [BATCH][NPT]
    const float* qX;      // 0.5*||row||^2
    const float* bmIn;    // [BATCH][128] per-16 max of (pot+cw) on cols
    const float* cwNext;  // cw paired with out when out is later used as cols
    const float* prev;    // previous row potential (averaging)
    float* out;           // [BATCH][NPT]
    float* tlsOut;        // log2e*(out+cwNext)
    float* bmOut;         // [BATCH][128] per-16 max of (out+cwNext)
};
struct CtArgs { CtSet s[4]; int average; };

// out[l] = qX[l] - lse_k( x_l . y_k + pot[k] + cw[k] ), opt 0.5*(prev + .)
// Column bias folded into MFMA C-operand (R2-proven rounding):
//   acc = L2E*x.y + (t_col - L2E*Tmax);  T = sum_k 2^acc;  lse = Tmax + ln T.
// Per tile: 2 MFMA + 8 exp2 + 8 add -- no wq multiply (vs R0's 9 exp + 8 fma).
// Grid (64,4,8)=2048 blocks = 8 waves/SIMD (R0's proven-best occupancy).
__global__ __launch_bounds__(256, 8) void ct_kernel(CtArgs args) {
    const CtSet cs = args.s[blockIdx.y];
    const int batch = blockIdx.z;
    const int row0 = blockIdx.x * RPB;
    const int tid  = threadIdx.x;
    const int w = tid >> 6, lane = tid & 63, n = lane & 15, quad = lane >> 4;
    const int qk = quad * 8;
    const size_t pbase = (size_t)batch * NPT * DIM;
    const size_t vbase = (size_t)batch * NPT;

    __shared__ float lsum[RPB][4];

    const u16* __restrict__ Ah = cs.Ah + pbase;
    const u16* __restrict__ Bh = cs.Bh + pbase;
    const float* __restrict__ tls = cs.tls + vbase;

    // A fragments for 2 row-strips: A[m=n][k=quad*8+j]
    half8 ah[STRIPS];
    #pragma unroll
    for (int s = 0; s < STRIPS; s++) {
        size_t off = (size_t)(row0 + s * 16 + n) * DIM + qk;
        ah[s] = *(const half8*)(Ah + off);
    }

    // Tmax = max_k (pot_k + cw_k): wave-local reduction of 128 16-row maxes
    float tmv = fmaxf(cs.bmIn[batch * 128 + lane], cs.bmIn[batch * 128 + 64 + lane]);
    #pragma unroll
    for (int m = 1; m < 64; m <<= 1) tmv = fmaxf(tmv, __shfl_xor(tmv, m, 64));
    const float Tmax = tmv;
    const float l2eTmax = L2E * Tmax;

    float sum[STRIPS][4];
    #pragma unroll
    for (int s = 0; s < STRIPS; s++)
        #pragma unroll
        for (int r = 0; r < 4; r++) sum[s][r] = 0.0f;

    // wave w owns cols [w*512, w*512+512): 32 tiles of 16, 2-deep reg prefetch,
    // NO barriers in the main loop -- waves fully decoupled.
    const int c0 = w * CPW + n;                    // this lane's col in tile 0
    const u16* bp = Bh + (size_t)c0 * DIM + qk;    // advances 16*DIM per tile
    const float* tp = tls + c0;

    half8 b0, b1;
    float t0, t1;
    b0 = *(const half8*)bp;  t0 = *tp;

    auto tile = [&](half8 b, float t) {
        float bias = t - l2eTmax;                  // per-lane column bias
        floatx4 ci = (floatx4){bias, bias, bias, bias};
        floatx4 acc[STRIPS];
        #pragma unroll
        for (int s = 0; s < STRIPS; s++)
            acc[s] = __builtin_amdgcn_mfma_f32_16x16x32_f16(ah[s], b, ci, 0, 0, 0);
        #pragma unroll
        for (int s = 0; s < STRIPS; s++)
            #pragma unroll
            for (int r = 0; r < 4; r++)
                sum[s][r] += exp2v(acc[s][r]);
    };

    #pragma unroll 1
    for (int ch = 0; ch < NT; ch += 2) {
        b1 = *(const half8*)(bp + (size_t)(ch + 1) * 16 * DIM);
        t1 = tp[(ch + 1) * 16];
        tile(b0, t0);
        if (ch + 2 < NT) {
            b0 = *(const half8*)(bp + (size_t)(ch + 2) * 16 * DIM);
            t0 = tp[(ch + 2) * 16];
        }
        tile(b1, t1);
    }

    // reduce over the 16 n-lanes (this wave's cols), then across waves via LDS
    #pragma unroll
    for (int s = 0; s < STRIPS; s++)
        #pragma unroll
        for (int r = 0; r < 4; r++) {
            float v = sum[s][r];
            #pragma unroll
            for (int m = 1; m < 16; m <<= 1) v += __shfl_xor(v, m, 64);
            if (n == 0) lsum[s * 16 + quad * 4 + r][w] = v;
        }
    __syncthreads();

    if (tid < RPB) {
        float T = (lsum[tid][0] + lsum[tid][1]) + (lsum[tid][2] + lsum[tid][3]);
        int l = row0 + tid;
        float lse = Tmax + __logf(T);
        float val = cs.qX[vbase + l] - lse;
        if (args.average) val = 0.5f * (cs.prev[vbase + l] + val);
        cs.out[vbase + l] = val;
        float tc = val + cs.cwNext[vbase + l];
        cs.tlsOut[vbase + l] = L2E * tc;
        float bm = tc;
        #pragma unroll
        for (int m = 1; m < 16; m <<= 1) bm = fmaxf(bm, __shfl_xor(bm, m, 64));
        if ((tid & 15) == 0)
            cs.bmOut[batch * 128 + blockIdx.x * STRIPS + (tid >> 4)] = bm;
    }
}

struct InitArgs {
    const float *x, *a, *y, *b;
    float *c_x, *c_y, *qx, *qy;
    u16 *xh, *yh, *xsh, *ysh;
    float *f0, *g0, *fx0, *fy0;
    float *tlsF0, *tlsG0, *tlsFx0, *tlsFy0;
    float *bmF0, *bmG0, *bmFx0, *bmFy0;
};

__global__ __launch_bounds__(256) void init_kernel(InitArgs ia) {
    int idx = blockIdx.x * 256 + threadIdx.x;
    if (idx >= BN) return;
    const float* xp = ia.x + (size_t)idx * DIM;
    const float* yp = ia.y + (size_t)idx * DIM;
    u32* xhp  = (u32*)ia.xh  + (size_t)idx * (DIM / 2);
    u32* yhp  = (u32*)ia.yh  + (size_t)idx * (DIM / 2);
    u32* xshp = (u32*)ia.xsh + (size_t)idx * (DIM / 2);
    u32* yshp = (u32*)ia.ysh + (size_t)idx * (DIM / 2);
    float sx = 0.f, sy = 0.f;
    #pragma unroll
    for (int d = 0; d < DIM; d += 2) {
        float v0 = xp[d], v1 = xp[d + 1];
        sx += v0 * v0 + v1 * v1;
        xhp[d / 2]  = (u32)f2h_bits(v0) | ((u32)f2h_bits(v1) << 16);
        xshp[d / 2] = (u32)f2h_bits(L2E * v0) | ((u32)f2h_bits(L2E * v1) << 16);
        float u0 = yp[d], u1 = yp[d + 1];
        sy += u0 * u0 + u1 * u1;
        yhp[d / 2]  = (u32)f2h_bits(u0) | ((u32)f2h_bits(u1) << 16);
        yshp[d / 2] = (u32)f2h_bits(L2E * u0) | ((u32)f2h_bits(L2E * u1) << 16);
    }
    float qxv = 0.5f * sx, qyv = 0.5f * sy;
    ia.qx[idx] = qxv; ia.qy[idx] = qyv;
    float cxv = __logf(ia.a[idx]) - qxv;
    float cyv = __logf(ia.b[idx]) - qyv;
    ia.c_x[idx] = cxv; ia.c_y[idx] = cyv;
    ia.f0[idx] = 0.f; ia.g0[idx] = 0.f; ia.fx0[idx] = 0.f; ia.fy0[idx] = 0.f;
    ia.tlsF0[idx] = L2E * cxv; ia.tlsG0[idx] = L2E * cyv;
    ia.tlsFx0[idx] = L2E * cxv; ia.tlsFy0[idx] = L2E * cyv;
    // per-16-row blockmax of (0 + cw)
    float mx = cxv, my = cyv;
    #pragma unroll
    for (int m = 1; m < 16; m <<= 1) {
        mx = fmaxf(mx, __shfl_xor(mx, m, 32));
        my = fmaxf(my, __shfl_xor(my, m, 32));
    }
    if ((threadIdx.x & 15) == 0) {
        int g = idx >> 4;   // == batch*128 + 16-row group
        ia.bmF0[g] = mx; ia.bmFx0[g] = mx;
        ia.bmG0[g] = my; ia.bmFy0[g] = my;
    }
}

__global__ __launch_bounds__(1024) void reduce_kernel(
        const float* __restrict__ a, const float* __restrict__ b,
        const float* __restrict__ ctA, const float* __restrict__ ctB,
        const float* __restrict__ ctX, const float* __restrict__ ctY,
        float* __restrict__ out) {
    float acc = 0.f;
    for (int idx = threadIdx.x; idx < BN; idx += 1024) {
        acc += a[idx] * (ctA[idx] - ctX[idx]) + b[idx] * (ctB[idx] - ctY[idx]);
    }
    #pragma unroll
    for (int off = 32; off > 0; off >>= 1) acc += __shfl_down(acc, off, 64);
    __shared__ float sm[16];
    if ((threadIdx.x & 63) == 0) sm[threadIdx.x >> 6] = acc;
    __syncthreads();
    if (threadIdx.x == 0) {
        float t = 0.f;
        #pragma unroll
        for (int i = 0; i < 16; i++) t += sm[i];
        out[0] = t / (float)BATCH;
    }
}

extern "C" void kernel_launch(void* const* d_in, const int* in_sizes, int n_in,
                              void* d_out, int out_size, void* d_ws, size_t ws_size,
                              hipStream_t stream) {
    const float* x = (const float*)d_in[0];
    const float* a = (const float*)d_in[1];
    const float* y = (const float*)d_in[2];
    const float* b = (const float*)d_in[3];
    float* out = (float*)d_out;

    float* ws = (float*)d_ws;
    float* c_x = ws + 0 * BN;
    float* c_y = ws + 1 * BN;
    float* qx  = ws + 2 * BN;
    float* qy  = ws + 3 * BN;
    float* fb[2]  = { ws + 4 * BN,  ws + 5 * BN };
    float* gb[2]  = { ws + 6 * BN,  ws + 7 * BN };
    float* fxb[2] = { ws + 8 * BN,  ws + 9 * BN };
    float* fyb[2] = { ws + 10 * BN, ws + 11 * BN };
    float* ctA = ws + 12 * BN;
    float* ctB = ws + 13 * BN;
    float* ctX = ws + 14 * BN;
    float* ctY = ws + 15 * BN;
    float* tlsF[2]  = { ws + 16 * BN, ws + 17 * BN };
    float* tlsG[2]  = { ws + 18 * BN, ws + 19 * BN };
    float* tlsFx[2] = { ws + 20 * BN, ws + 21 * BN };
    float* tlsFy[2] = { ws + 22 * BN, ws + 23 * BN };
    float* dummyT = ws + 24 * BN;
    float* small = ws + 25 * BN;
    float* bmF[2]  = { small + 0 * 1024, small + 1 * 1024 };
    float* bmG[2]  = { small + 2 * 1024, small + 3 * 1024 };
    float* bmFx[2] = { small + 4 * 1024, small + 5 * 1024 };
    float* bmFy[2] = { small + 6 * 1024, small + 7 * 1024 };
    float* dummyB = small + 8 * 1024;
    u16* bf = (u16*)(small + 10 * 1024);
    const size_t AS = (size_t)BN * DIM;
    u16* xh  = bf + 0 * AS;   // plain fp16 x
    u16* yh  = bf + 1 * AS;   // plain fp16 y
    u16* xsh = bf + 2 * AS;   // L2E-scaled fp16 x
    u16* ysh = bf + 3 * AS;   // L2E-scaled fp16 y

    InitArgs ia;
    ia.x = x; ia.a = a; ia.y = y; ia.b = b;
    ia.c_x = c_x; ia.c_y = c_y; ia.qx = qx; ia.qy = qy;
    ia.xh = xh; ia.yh = yh; ia.xsh = xsh; ia.ysh = ysh;
    ia.f0 = fb[0]; ia.g0 = gb[0]; ia.fx0 = fxb[0]; ia.fy0 = fyb[0];
    ia.tlsF0 = tlsF[0]; ia.tlsG0 = tlsG[0]; ia.tlsFx0 = tlsFx[0]; ia.tlsFy0 = tlsFy[0];
    ia.bmF0 = bmF[0]; ia.bmG0 = bmG[0]; ia.bmFx0 = bmFx[0]; ia.bmFy0 = bmFy[0];
    init_kernel<<<BN / 256, 256, 0, stream>>>(ia);

    dim3 grid(NPT / RPB, 4, BATCH);
    int cur = 0;
    for (int it = 0; it < 10; it++) {
        CtArgs ar;
        ar.average = 1;
        // set0: fn = ct(g, log_b, kxy): rows X, cols Y
        ar.s[0] = { xh, ysh, tlsG[cur], qx, bmG[cur], c_x,
                    fb[cur], fb[1 - cur], tlsF[1 - cur], bmF[1 - cur] };
        // set1: gn = ct(f, log_a, kyx): rows Y, cols X
        ar.s[1] = { yh, xsh, tlsF[cur], qy, bmF[cur], c_y,
                    gb[cur], gb[1 - cur], tlsG[1 - cur], bmG[1 - cur] };
        // set2: sym x: rows X, cols X
        ar.s[2] = { xh, xsh, tlsFx[cur], qx, bmFx[cur], c_x,
                    fxb[cur], fxb[1 - cur], tlsFx[1 - cur], bmFx[1 - cur] };
        // set3: sym y: rows Y, cols Y
        ar.s[3] = { yh, ysh, tlsFy[cur], qy, bmFy[cur], c_y,
                    fyb[cur], fyb[1 - cur], tlsFy[1 - cur], bmFy[1 - cur] };
        ct_kernel<<<grid, 256, 0, stream>>>(ar);
        cur ^= 1;
    }

    CtArgs fin;
    fin.average = 0;
    fin.s[0] = { xh, ysh, tlsG[cur], qx, bmG[cur], c_x, fb[cur], ctA, dummyT, dummyB };
    fin.s[1] = { yh, xsh, tlsF[cur], qy, bmF[cur], c_y, gb[cur], ctB, dummyT, dummyB };
    fin.s[2] = { xh, xsh, tlsFx[cur], qx, bmFx[cur], c_x, fxb[cur], ctX, dummyT, dummyB };
    fin.s[3] = { yh, ysh, tlsFy[cur], qy, bmFy[cur], c_y, fyb[cur], ctY, dummyT, dummyB };
    ct_kernel<<<grid, 256, 0, stream>>>(fin);

    reduce_kernel<<<1, 1024, 0, stream>>>(a, b, ctA, ctB, ctX, ctY, out);
}

// Round 10
// 311.807 us; speedup vs baseline: 6.4321x; 1.0604x over previous
//
#include <hip/hip_runtime.h>
#include <math.h>

#define BATCH 8
#define NPT   2048
#define DIM   32
#define RPB   32                      // rows per block: 2 strips of 16
#define STRIPS (RPB / 16)
#define CPW   (NPT / 4)               // 512 cols per wave
#define NT    (CPW / 16)              // 32 col-tiles of 16 per wave
#define L2E   1.44269504088896f
#define BN    (BATCH * NPT)

typedef __attribute__((ext_vector_type(8))) _Float16 half8;
typedef __attribute__((ext_vector_type(4))) float floatx4;
typedef unsigned short u16;
typedef unsigned int u32;

__device__ __forceinline__ u16 f2h_bits(float v) {
    _Float16 h = (_Float16)v;
    return *(u16*)&h;
}
__device__ __forceinline__ float exp2v(float x) { return __builtin_amdgcn_exp2f(x); }

struct CtSet {
    const u16* Ah;        // row-side plain fp16 [BATCH][NPT][DIM]
    const u16* Bh;        // col-side log2e-scaled fp16
    const float* tls;     // log2e*(pot+cw) on cols [BATCH][NPT]
    const float* qX;      // 0.5*||row||^2
    const float* bmIn;    // [BATCH][128] per-16 max of (pot+cw) on cols
    const float* cwNext;  // cw paired with out when out is later used as cols
    const float* prev;    // previous row potential (averaging)
    float* out;           // [BATCH][NPT]
    float* tlsOut;        // log2e*(out+cwNext)
    float* bmOut;         // [BATCH][128] per-16 max of (out+cwNext)
};
struct CtArgs { CtSet s[4]; int average; };

// out[l] = qX[l] - lse_k( x_l . y_k + pot[k] + cw[k] ), opt 0.5*(prev + .)
// Column bias folded into MFMA C-operand (R2/R8-proven rounding):
//   acc = L2E*x.y + (t_col - L2E*Tmax);  T = sum_k 2^acc;  lse = Tmax + ln T.
// XCD PINNING: 1-D grid, batch = bid & 7. Linear block IDs round-robin
// across the 8 XCDs, so all blocks of batch b land on XCD b. Per-XCD L2
// hot set drops from ~4+ MB (all batches: at the 4 MiB capacity edge ->
// MALL thrash) to ~0.6 MB (one batch's xsh+ysh panels + A rows + tls)
// -> B-stream L2-resident. Index remap only; math identical to R8.
__global__ __launch_bounds__(256, 8) void ct_kernel(CtArgs args) {
    const int bid  = blockIdx.x;
    const int batch = bid & 7;            // batch == XCD (dispatch round-robin)
    const int rest  = bid >> 3;           // 0..255 within the XCD
    const int slice = rest & 3;
    const int xb    = rest >> 2;          // 0..63 row-block
    const CtSet cs = args.s[slice];
    const int row0 = xb * RPB;
    const int tid  = threadIdx.x;
    const int w = tid >> 6, lane = tid & 63, n = lane & 15, quad = lane >> 4;
    const int qk = quad * 8;
    const size_t pbase = (size_t)batch * NPT * DIM;
    const size_t vbase = (size_t)batch * NPT;

    __shared__ float lsum[RPB][4];

    const u16* __restrict__ Ah = cs.Ah + pbase;
    const u16* __restrict__ Bh = cs.Bh + pbase;
    const float* __restrict__ tls = cs.tls + vbase;

    // A fragments for 2 row-strips: A[m=n][k=quad*8+j]
    half8 ah[STRIPS];
    #pragma unroll
    for (int s = 0; s < STRIPS; s++) {
        size_t off = (size_t)(row0 + s * 16 + n) * DIM + qk;
        ah[s] = *(const half8*)(Ah + off);
    }

    // Tmax = max_k (pot_k + cw_k): wave-local reduction of 128 16-row maxes
    float tmv = fmaxf(cs.bmIn[batch * 128 + lane], cs.bmIn[batch * 128 + 64 + lane]);
    #pragma unroll
    for (int m = 1; m < 64; m <<= 1) tmv = fmaxf(tmv, __shfl_xor(tmv, m, 64));
    const float Tmax = tmv;
    const float l2eTmax = L2E * Tmax;

    float sum[STRIPS][4];
    #pragma unroll
    for (int s = 0; s < STRIPS; s++)
        #pragma unroll
        for (int r = 0; r < 4; r++) sum[s][r] = 0.0f;

    // wave w owns cols [w*512, w*512+512): 32 tiles of 16, 2-deep reg prefetch,
    // NO barriers in the main loop -- waves fully decoupled.
    const int c0 = w * CPW + n;                    // this lane's col in tile 0
    const u16* bp = Bh + (size_t)c0 * DIM + qk;    // advances 16*DIM per tile
    const float* tp = tls + c0;

    half8 b0, b1;
    float t0, t1;
    b0 = *(const half8*)bp;  t0 = *tp;

    auto tile = [&](half8 b, float t) {
        float bias = t - l2eTmax;                  // per-lane column bias
        floatx4 ci = (floatx4){bias, bias, bias, bias};
        floatx4 acc[STRIPS];
        #pragma unroll
        for (int s = 0; s < STRIPS; s++)
            acc[s] = __builtin_amdgcn_mfma_f32_16x16x32_f16(ah[s], b, ci, 0, 0, 0);
        #pragma unroll
        for (int s = 0; s < STRIPS; s++)
            #pragma unroll
            for (int r = 0; r < 4; r++)
                sum[s][r] += exp2v(acc[s][r]);
    };

    #pragma unroll 1
    for (int ch = 0; ch < NT; ch += 2) {
        b1 = *(const half8*)(bp + (size_t)(ch + 1) * 16 * DIM);
        t1 = tp[(ch + 1) * 16];
        tile(b0, t0);
        if (ch + 2 < NT) {
            b0 = *(const half8*)(bp + (size_t)(ch + 2) * 16 * DIM);
            t0 = tp[(ch + 2) * 16];
        }
        tile(b1, t1);
    }

    // reduce over the 16 n-lanes (this wave's cols), then across waves via LDS
    #pragma unroll
    for (int s = 0; s < STRIPS; s++)
        #pragma unroll
        for (int r = 0; r < 4; r++) {
            float v = sum[s][r];
            #pragma unroll
            for (int m = 1; m < 16; m <<= 1) v += __shfl_xor(v, m, 64);
            if (n == 0) lsum[s * 16 + quad * 4 + r][w] = v;
        }
    __syncthreads();

    if (tid < RPB) {
        float T = (lsum[tid][0] + lsum[tid][1]) + (lsum[tid][2] + lsum[tid][3]);
        int l = row0 + tid;
        float lse = Tmax + __logf(T);
        float val = cs.qX[vbase + l] - lse;
        if (args.average) val = 0.5f * (cs.prev[vbase + l] + val);
        cs.out[vbase + l] = val;
        float tc = val + cs.cwNext[vbase + l];
        cs.tlsOut[vbase + l] = L2E * tc;
        float bm = tc;
        #pragma unroll
        for (int m = 1; m < 16; m <<= 1) bm = fmaxf(bm, __shfl_xor(bm, m, 64));
        if ((tid & 15) == 0)
            cs.bmOut[batch * 128 + xb * STRIPS + (tid >> 4)] = bm;
    }
}

struct InitArgs {
    const float *x, *a, *y, *b;
    float *c_x, *c_y, *qx, *qy;
    u16 *xh, *yh, *xsh, *ysh;
    float *f0, *g0, *fx0, *fy0;
    float *tlsF0, *tlsG0, *tlsFx0, *tlsFy0;
    float *bmF0, *bmG0, *bmFx0, *bmFy0;
};

__global__ __launch_bounds__(256) void init_kernel(InitArgs ia) {
    int idx = blockIdx.x * 256 + threadIdx.x;
    if (idx >= BN) return;
    const float* xp = ia.x + (size_t)idx * DIM;
    const float* yp = ia.y + (size_t)idx * DIM;
    u32* xhp  = (u32*)ia.xh  + (size_t)idx * (DIM / 2);
    u32* yhp  = (u32*)ia.yh  + (size_t)idx * (DIM / 2);
    u32* xshp = (u32*)ia.xsh + (size_t)idx * (DIM / 2);
    u32* yshp = (u32*)ia.ysh + (size_t)idx * (DIM / 2);
    float sx = 0.f, sy = 0.f;
    #pragma unroll
    for (int d = 0; d < DIM; d += 2) {
        float v0 = xp[d], v1 = xp[d + 1];
        sx += v0 * v0 + v1 * v1;
        xhp[d / 2]  = (u32)f2h_bits(v0) | ((u32)f2h_bits(v1) << 16);
        xshp[d / 2] = (u32)f2h_bits(L2E * v0) | ((u32)f2h_bits(L2E * v1) << 16);
        float u0 = yp[d], u1 = yp[d + 1];
        sy += u0 * u0 + u1 * u1;
        yhp[d / 2]  = (u32)f2h_bits(u0) | ((u32)f2h_bits(u1) << 16);
        yshp[d / 2] = (u32)f2h_bits(L2E * u0) | ((u32)f2h_bits(L2E * u1) << 16);
    }
    float qxv = 0.5f * sx, qyv = 0.5f * sy;
    ia.qx[idx] = qxv; ia.qy[idx] = qyv;
    float cxv = __logf(ia.a[idx]) - qxv;
    float cyv = __logf(ia.b[idx]) - qyv;
    ia.c_x[idx] = cxv; ia.c_y[idx] = cyv;
    ia.f0[idx] = 0.f; ia.g0[idx] = 0.f; ia.fx0[idx] = 0.f; ia.fy0[idx] = 0.f;
    ia.tlsF0[idx] = L2E * cxv; ia.tlsG0[idx] = L2E * cyv;
    ia.tlsFx0[idx] = L2E * cxv; ia.tlsFy0[idx] = L2E * cyv;
    // per-16-row blockmax of (0 + cw)
    float mx = cxv, my = cyv;
    #pragma unroll
    for (int m = 1; m < 16; m <<= 1) {
        mx = fmaxf(mx, __shfl_xor(mx, m, 32));
        my = fmaxf(my, __shfl_xor(my, m, 32));
    }
    if ((threadIdx.x & 15) == 0) {
        int g = idx >> 4;   // == batch*128 + 16-row group
        ia.bmF0[g] = mx; ia.bmFx0[g] = mx;
        ia.bmG0[g] = my; ia.bmFy0[g] = my;
    }
}

__global__ __launch_bounds__(1024) void reduce_kernel(
        const float* __restrict__ a, const float* __restrict__ b,
        const float* __restrict__ ctA, const float* __restrict__ ctB,
        const float* __restrict__ ctX, const float* __restrict__ ctY,
        float* __restrict__ out) {
    float acc = 0.f;
    for (int idx = threadIdx.x; idx < BN; idx += 1024) {
        acc += a[idx] * (ctA[idx] - ctX[idx]) + b[idx] * (ctB[idx] - ctY[idx]);
    }
    #pragma unroll
    for (int off = 32; off > 0; off >>= 1) acc += __shfl_down(acc, off, 64);
    __shared__ float sm[16];
    if ((threadIdx.x & 63) == 0) sm[threadIdx.x >> 6] = acc;
    __syncthreads();
    if (threadIdx.x == 0) {
        float t = 0.f;
        #pragma unroll
        for (int i = 0; i < 16; i++) t += sm[i];
        out[0] = t / (float)BATCH;
    }
}

extern "C" void kernel_launch(void* const* d_in, const int* in_sizes, int n_in,
                              void* d_out, int out_size, void* d_ws, size_t ws_size,
                              hipStream_t stream) {
    const float* x = (const float*)d_in[0];
    const float* a = (const float*)d_in[1];
    const float* y = (const float*)d_in[2];
    const float* b = (const float*)d_in[3];
    float* out = (float*)d_out;

    float* ws = (float*)d_ws;
    float* c_x = ws + 0 * BN;
    float* c_y = ws + 1 * BN;
    float* qx  = ws + 2 * BN;
    float* qy  = ws + 3 * BN;
    float* fb[2]  = { ws + 4 * BN,  ws + 5 * BN };
    float* gb[2]  = { ws + 6 * BN,  ws + 7 * BN };
    float* fxb[2] = { ws + 8 * BN,  ws + 9 * BN };
    float* fyb[2] = { ws + 10 * BN, ws + 11 * BN };
    float* ctA = ws + 12 * BN;
    float* ctB = ws + 13 * BN;
    float* ctX = ws + 14 * BN;
    float* ctY = ws + 15 * BN;
    float* tlsF[2]  = { ws + 16 * BN, ws + 17 * BN };
    float* tlsG[2]  = { ws + 18 * BN, ws + 19 * BN };
    float* tlsFx[2] = { ws + 20 * BN, ws + 21 * BN };
    float* tlsFy[2] = { ws + 22 * BN, ws + 23 * BN };
    float* dummyT = ws + 24 * BN;
    float* small = ws + 25 * BN;
    float* bmF[2]  = { small + 0 * 1024, small + 1 * 1024 };
    float* bmG[2]  = { small + 2 * 1024, small + 3 * 1024 };
    float* bmFx[2] = { small + 4 * 1024, small + 5 * 1024 };
    float* bmFy[2] = { small + 6 * 1024, small + 7 * 1024 };
    float* dummyB = small + 8 * 1024;
    u16* bf = (u16*)(small + 10 * 1024);
    const size_t AS = (size_t)BN * DIM;
    u16* xh  = bf + 0 * AS;   // plain fp16 x
    u16* yh  = bf + 1 * AS;   // plain fp16 y
    u16* xsh = bf + 2 * AS;   // L2E-scaled fp16 x
    u16* ysh = bf + 3 * AS;   // L2E-scaled fp16 y

    InitArgs ia;
    ia.x = x; ia.a = a; ia.y = y; ia.b = b;
    ia.c_x = c_x; ia.c_y = c_y; ia.qx = qx; ia.qy = qy;
    ia.xh = xh; ia.yh = yh; ia.xsh = xsh; ia.ysh = ysh;
    ia.f0 = fb[0]; ia.g0 = gb[0]; ia.fx0 = fxb[0]; ia.fy0 = fyb[0];
    ia.tlsF0 = tlsF[0]; ia.tlsG0 = tlsG[0]; ia.tlsFx0 = tlsFx[0]; ia.tlsFy0 = tlsFy[0];
    ia.bmF0 = bmF[0]; ia.bmG0 = bmG[0]; ia.bmFx0 = bmFx[0]; ia.bmFy0 = bmFy[0];
    init_kernel<<<BN / 256, 256, 0, stream>>>(ia);

    const int nblk = (NPT / RPB) * 4 * BATCH;   // 2048, 1-D for XCD pinning
    int cur = 0;
    for (int it = 0; it < 10; it++) {
        CtArgs ar;
        ar.average = 1;
        // set0: fn = ct(g, log_b, kxy): rows X, cols Y
        ar.s[0] = { xh, ysh, tlsG[cur], qx, bmG[cur], c_x,
                    fb[cur], fb[1 - cur], tlsF[1 - cur], bmF[1 - cur] };
        // set1: gn = ct(f, log_a, kyx): rows Y, cols X
        ar.s[1] = { yh, xsh, tlsF[cur], qy, bmF[cur], c_y,
                    gb[cur], gb[1 - cur], tlsG[1 - cur], bmG[1 - cur] };
        // set2: sym x: rows X, cols X
        ar.s[2] = { xh, xsh, tlsFx[cur], qx, bmFx[cur], c_x,
                    fxb[cur], fxb[1 - cur], tlsFx[1 - cur], bmFx[1 - cur] };
        // set3: sym y: rows Y, cols Y
        ar.s[3] = { yh, ysh, tlsFy[cur], qy, bmFy[cur], c_y,
                    fyb[cur], fyb[1 - cur], tlsFy[1 - cur], bmFy[1 - cur] };
        ct_kernel<<<nblk, 256, 0, stream>>>(ar);
        cur ^= 1;
    }

    CtArgs fin;
    fin.average = 0;
    fin.s[0] = { xh, ysh, tlsG[cur], qx, bmG[cur], c_x, fb[cur], ctA, dummyT, dummyB };
    fin.s[1] = { yh, xsh, tlsF[cur], qy, bmF[cur], c_y, gb[cur], ctB, dummyT, dummyB };
    fin.s[2] = { xh, xsh, tlsFx[cur], qx, bmFx[cur], c_x, fxb[cur], ctX, dummyT, dummyB };
    fin.s[3] = { yh, ysh, tlsFy[cur], qy, bmFy[cur], c_y, fyb[cur], ctY, dummyT, dummyB };
    ct_kernel<<<nblk, 256, 0, stream>>>(fin);

    reduce_kernel<<<1, 1024, 0, stream>>>(a, b, ctA, ctB, ctX, ctY, out);
}